// Round 9
// baseline (151.924 us; speedup 1.0000x reference)
//
#include <hip/hip_runtime.h>

// 5-layer MLP [B,64]->32->12->8->6->2, fp32.
// R8 math (plain fmaf -> s_load weights on scalar pipe, 2 rows/lane) with
// doubled occupancy: chunk = 8 cols x 128 rows = 4KB, double-buffered
// (8KB/wave), BLOCK=256 (4 waves, 32KB/block -> 5 blocks/CU = 20 waves/CU).
// LDS layout: 32 super-rows x 128B; super-row R holds rows {2R,2R+1,2R+64,
// 2R+65} x 32B as 8 16B slots, slot s = u ^ (R&7), u = h + 2p + 4q
// (h=16B-half, p=row parity, q=row>=64). DMA dest linear, per-lane GLOBAL
// source carries the inverse permutation (verified bijective round-trip).
// Counted s_waitcnt vmcnt(4); no __syncthreads (LDS wave-private).

typedef __attribute__((address_space(3))) void* as3p;
typedef const __attribute__((address_space(1))) void* as1p;

#define BLOCK 256        // 4 waves/block
#define NT 2             // 128-row tiles per wave
#define TILE_ROWS 128
#define CHUNKS_PER_TILE 8
#define TOTAL_CHUNKS (NT * CHUNKS_PER_TILE)

template <int IN, int OUT, bool RELU>
__device__ __forceinline__ void layer2(const float* __restrict__ W,
                                       const float* __restrict__ b,
                                       const float* in0, const float* in1,
                                       float* out0, float* out1) {
#pragma unroll
    for (int o = 0; o < OUT; ++o) { out0[o] = b[o]; out1[o] = b[o]; }
#pragma unroll
    for (int i = 0; i < IN; ++i) {
        const float v0 = in0[i];
        const float v1 = in1[i];
#pragma unroll
        for (int o = 0; o < OUT; ++o) {
            const float w = W[i * OUT + o];     // uniform -> s_load
            out0[o] = fmaf(v0, w, out0[o]);
            out1[o] = fmaf(v1, w, out1[o]);
        }
    }
    if (RELU) {
#pragma unroll
        for (int o = 0; o < OUT; ++o) {
            out0[o] = fmaxf(out0[o], 0.0f);
            out1[o] = fmaxf(out1[o], 0.0f);
        }
    }
}

__global__ __launch_bounds__(BLOCK, 4) void mlp_kernel(
        const float* __restrict__ x,
        const float* __restrict__ W0, const float* __restrict__ b0,
        const float* __restrict__ W1, const float* __restrict__ b1,
        const float* __restrict__ W2, const float* __restrict__ b2,
        const float* __restrict__ W3, const float* __restrict__ b3,
        const float* __restrict__ W4, const float* __restrict__ b4,
        float* __restrict__ out, int nrows) {
    extern __shared__ char lds[];
    const int t = threadIdx.x;
    const int wv = t >> 6;
    const int lane = t & 63;
    char* bufA = lds + wv * 8192;    // 4KB chunk buffer
    char* bufB = bufA + 4096;        // 4KB chunk buffer

    const long long wrow0 =
        ((long long)blockIdx.x * 4 + wv) * (NT * TILE_ROWS);
    const char* xbase = reinterpret_cast<const char*>(x + wrow0 * 64);

    // Per-lane constant staging source offset (inverse of read swizzle).
    // DMA call k writes unit P = 64k + lane; R = P>>3, s = P&7,
    // u = s ^ (R&7) = (lane&7) ^ (lane>>3)  (k*8 drops mod 8).
    const int u = (lane & 7) ^ (lane >> 3);
    const int rowbase = 2 * (lane >> 3) + ((u >> 1) & 1) + 64 * ((u >> 2) & 1);
    const int stage_off = rowbase * 256 + (u & 1) * 16;   // + 4096*k + 32*c

    // Per-lane LDS read offsets. Lane L: R=L>>1, p=L&1; unit (q,h) at
    // R*128 + ((h + 2p + 4q) ^ (R&7))*16.
    const int R = lane >> 1;
    const int p = lane & 1;
    const int r7 = R & 7;
    int roff[4];
#pragma unroll
    for (int qh = 0; qh < 4; ++qh) {           // qh = 2*q + h
        const int uu = (qh & 1) + 2 * p + 4 * (qh >> 1);
        roff[qh] = R * 128 + ((uu ^ r7) << 4);
    }

    // Stage global chunk gc (tile gc>>3, col-chunk gc&7) into buf.
    auto STAGE = [&](int gc, char* buf) {
        const char* s0 = xbase + (gc >> 3) * (TILE_ROWS * 256) +
                         (gc & 7) * 32 + stage_off;
#pragma unroll
        for (int k = 0; k < 4; ++k)
            __builtin_amdgcn_global_load_lds((as1p)(s0 + k * 4096),
                                             (as3p)(buf + k * 1024), 16, 0, 0);
    };

    STAGE(0, bufA);   // prologue

#pragma unroll 1
    for (int tt = 0; tt < NT; ++tt) {
        float acc0[32], acc1[32];
#pragma unroll
        for (int o = 0; o < 32; ++o) {
            const float bb = b0[o];
            acc0[o] = bb;
            acc1[o] = bb;
        }

#pragma unroll 1
        for (int c = 0; c < CHUNKS_PER_TILE; ++c) {
            const int gc = tt * CHUNKS_PER_TILE + c;
            char* cur = (gc & 1) ? bufB : bufA;
            char* oth = (gc & 1) ? bufA : bufB;

            if (gc + 1 < TOTAL_CHUNKS) {
                STAGE(gc + 1, oth);
                // 4 new loads in flight; drain everything older.
                asm volatile("s_waitcnt vmcnt(4)" ::: "memory");
            } else {
                asm volatile("s_waitcnt vmcnt(0)" ::: "memory");
            }
            __builtin_amdgcn_sched_barrier(0);

            // 4x ds_read_b128: rows L and L+64, 8 floats each.
            float xr0[8], xr1[8];
            {
                const float4 v0 = *reinterpret_cast<const float4*>(cur + roff[0]);
                const float4 v1 = *reinterpret_cast<const float4*>(cur + roff[1]);
                const float4 v2 = *reinterpret_cast<const float4*>(cur + roff[2]);
                const float4 v3 = *reinterpret_cast<const float4*>(cur + roff[3]);
                xr0[0]=v0.x; xr0[1]=v0.y; xr0[2]=v0.z; xr0[3]=v0.w;
                xr0[4]=v1.x; xr0[5]=v1.y; xr0[6]=v1.z; xr0[7]=v1.w;
                xr1[0]=v2.x; xr1[1]=v2.y; xr1[2]=v2.z; xr1[3]=v2.w;
                xr1[4]=v3.x; xr1[5]=v3.y; xr1[6]=v3.z; xr1[7]=v3.w;
            }

            // Layer-0 partial: 8 i-values x 32 outputs, 2 rows per weight.
            const float* Wc = W0 + (c << 8);   // 8 rows * 32 cols per chunk
#pragma unroll
            for (int idx = 0; idx < 8; ++idx) {
                const float v0 = xr0[idx];
                const float v1 = xr1[idx];
#pragma unroll
                for (int o = 0; o < 32; ++o) {
                    const float w = Wc[idx * 32 + o];
                    acc0[o] = fmaf(v0, w, acc0[o]);
                    acc1[o] = fmaf(v1, w, acc1[o]);
                }
            }
        }

        // ReLU on h0
#pragma unroll
        for (int o = 0; o < 32; ++o) {
            acc0[o] = fmaxf(acc0[o], 0.0f);
            acc1[o] = fmaxf(acc1[o], 0.0f);
        }

        // Tail layers (next tile's chunk-0 DMA flies during these).
        float h1a[12], h1b[12], h2a[8], h2b[8], h3a[6], h3b[6], h4a[2], h4b[2];
        layer2<32, 12, true>(W1, b1, acc0, acc1, h1a, h1b);
        layer2<12, 8, true>(W2, b2, h1a, h1b, h2a, h2b);
        layer2<8, 6, true>(W3, b3, h2a, h2b, h3a, h3b);
        layer2<6, 2, false>(W4, b4, h3a, h3b, h4a, h4b);

        const long long r = wrow0 + (long long)tt * TILE_ROWS + lane;
        float2* outv = reinterpret_cast<float2*>(out);
        outv[r]      = make_float2(h4a[0], h4a[1]);
        outv[r + 64] = make_float2(h4b[0], h4b[1]);
    }
}

extern "C" void kernel_launch(void* const* d_in, const int* in_sizes, int n_in,
                              void* d_out, int out_size, void* d_ws, size_t ws_size,
                              hipStream_t stream) {
    const float* x  = (const float*)d_in[0];
    const float* W0 = (const float*)d_in[1];
    const float* b0 = (const float*)d_in[2];
    const float* W1 = (const float*)d_in[3];
    const float* b1 = (const float*)d_in[4];
    const float* W2 = (const float*)d_in[5];
    const float* b2 = (const float*)d_in[6];
    const float* W3 = (const float*)d_in[7];
    const float* b3 = (const float*)d_in[8];
    const float* W4 = (const float*)d_in[9];
    const float* b4 = (const float*)d_in[10];
    float* out = (float*)d_out;

    const int nrows = in_sizes[0] / 64;                      // 1,048,576
    const int rows_per_block = 4 * NT * TILE_ROWS;           // 1024
    const int grid = nrows / rows_per_block;                 // 1024 (exact)
    const size_t shmem = 4 * 8192;                           // 32 KiB/block

    mlp_kernel<<<grid, BLOCK, shmem, stream>>>(x, W0, b0, W1, b1, W2, b2,
                                               W3, b3, W4, b4, out, nrows);
}

// Round 10
// 89.783 us; speedup vs baseline: 1.6921x; 1.6921x over previous
//
#include <hip/hip_runtime.h>

// 5-layer MLP [B,64]->32->12->8->6->2, fp32.
// R6 staging geometry (proven: clean fetch, ~0 conflicts) + R8 math (plain
// fmaf -> s_load weights, SLP-packed v_pk_fma_f32). Wave-private 8KB LDS
// (2 x 4KB chunk double-buffer) -> ~16-20 waves/CU. Chunk = 64 rows x 64B
// (full cachelines). Counted s_waitcnt vmcnt(4); no __syncthreads.

typedef __attribute__((address_space(3))) void* as3p;
typedef const __attribute__((address_space(1))) void* as1p;

#define BLOCK 256   // 4 waves/block
#define NT 2        // 64-row tiles per wave

template <int IN, int OUT, bool RELU>
__device__ __forceinline__ void layer(const float* __restrict__ W,
                                      const float* __restrict__ b,
                                      const float* h_in, float* h_out) {
#pragma unroll
    for (int o = 0; o < OUT; ++o) h_out[o] = b[o];
#pragma unroll
    for (int i = 0; i < IN; ++i) {
        const float v = h_in[i];
#pragma unroll
        for (int o = 0; o < OUT; ++o)
            h_out[o] = fmaf(v, W[i * OUT + o], h_out[o]);   // uniform -> s_load
    }
    if (RELU) {
#pragma unroll
        for (int o = 0; o < OUT; ++o) h_out[o] = fmaxf(h_out[o], 0.0f);
    }
}

__global__ __launch_bounds__(BLOCK) void mlp_kernel(
        const float* __restrict__ x,
        const float* __restrict__ W0, const float* __restrict__ b0,
        const float* __restrict__ W1, const float* __restrict__ b1,
        const float* __restrict__ W2, const float* __restrict__ b2,
        const float* __restrict__ W3, const float* __restrict__ b3,
        const float* __restrict__ W4, const float* __restrict__ b4,
        float* __restrict__ out, int nrows) {
    extern __shared__ char lds[];
    const int t = threadIdx.x;
    const int wv = t >> 6;
    const int lane = t & 63;
    char* buf0 = lds + wv * 8192;
    char* buf1 = buf0 + 4096;

    const long long row0 = ((long long)blockIdx.x * 4 + wv) * (NT * 64);
    const char* xbase = reinterpret_cast<const char*>(x + row0 * 64);

    // --- R6-proven per-lane staging source offset (inverse of read swizzle).
    const int h = lane >> 3;
    const int q = (lane & 7) ^ h;
    const int stage_off = (2 * h + (q >> 2)) * 256 + (q & 3) * 16;

    // --- R6-proven per-lane LDS read offsets (row r = lane).
    const int R = lane >> 1;
    const int p2 = lane & 1;
    const int r7 = R & 7;
    int roff[4];
#pragma unroll
    for (int j = 0; j < 4; ++j)
        roff[j] = R * 128 + (((j + 4 * p2) ^ r7) << 4);

    // Stage global chunk gc (tile gc>>2, col-chunk gc&3) into buf.
    auto STAGE = [&](int gc, char* buf) {
        const char* s0 = xbase + (gc >> 2) * (64 * 256) + (gc & 3) * 64 +
                         stage_off;
#pragma unroll
        for (int k = 0; k < 4; ++k)
            __builtin_amdgcn_global_load_lds((as1p)(s0 + k * 4096),
                                             (as3p)(buf + k * 1024), 16, 0, 0);
    };

    STAGE(0, buf0);   // prologue

#pragma unroll 1
    for (int tt = 0; tt < NT; ++tt) {
        float acc[32];
#pragma unroll
        for (int o = 0; o < 32; ++o) acc[o] = b0[o];

#pragma unroll 1
        for (int c = 0; c < 4; ++c) {
            const int gc = tt * 4 + c;
            char* cur = (gc & 1) ? buf1 : buf0;
            char* oth = (gc & 1) ? buf0 : buf1;

            if (gc + 1 < NT * 4) {
                STAGE(gc + 1, oth);
                // 4 new loads in flight; drain only the current chunk's.
                asm volatile("s_waitcnt vmcnt(4)" ::: "memory");
            } else {
                asm volatile("s_waitcnt vmcnt(0)" ::: "memory");
            }
            __builtin_amdgcn_sched_barrier(0);

            // Conflict-free swizzled reads: 4x ds_read_b128 (16 floats).
            float xr[16];
#pragma unroll
            for (int j = 0; j < 4; ++j) {
                const float4 v =
                    *reinterpret_cast<const float4*>(cur + roff[j]);
                xr[4 * j + 0] = v.x; xr[4 * j + 1] = v.y;
                xr[4 * j + 2] = v.z; xr[4 * j + 3] = v.w;
            }

            // Layer-0 partial: 16 i-values x 32 outputs, plain fmaf
            // (compiler SLP-packs adjacent o into v_pk_fma_f32, weights
            // ride the scalar pipe as SGPR pairs).
            const float* Wc = W0 + (c << 9);   // 16 rows * 32 cols
#pragma unroll
            for (int idx = 0; idx < 16; ++idx) {
                const float v = xr[idx];
#pragma unroll
                for (int o = 0; o < 32; ++o)
                    acc[o] = fmaf(v, Wc[idx * 32 + o], acc[o]);
            }
        }

        // ReLU on h0
#pragma unroll
        for (int o = 0; o < 32; ++o) acc[o] = fmaxf(acc[o], 0.0f);

        // Tail layers (next tile's chunk-0 DMA flies during these).
        float h1[12], h2[8], h3[6], h4[2];
        layer<32, 12, true>(W1, b1, acc, h1);
        layer<12, 8, true>(W2, b2, h1, h2);
        layer<8, 6, true>(W3, b3, h2, h3);
        layer<6, 2, false>(W4, b4, h3, h4);

        reinterpret_cast<float2*>(out)[row0 + tt * 64 + lane] =
            make_float2(h4[0], h4[1]);
    }
}

extern "C" void kernel_launch(void* const* d_in, const int* in_sizes, int n_in,
                              void* d_out, int out_size, void* d_ws, size_t ws_size,
                              hipStream_t stream) {
    const float* x  = (const float*)d_in[0];
    const float* W0 = (const float*)d_in[1];
    const float* b0 = (const float*)d_in[2];
    const float* W1 = (const float*)d_in[3];
    const float* b1 = (const float*)d_in[4];
    const float* W2 = (const float*)d_in[5];
    const float* b2 = (const float*)d_in[6];
    const float* W3 = (const float*)d_in[7];
    const float* b3 = (const float*)d_in[8];
    const float* W4 = (const float*)d_in[9];
    const float* b4 = (const float*)d_in[10];
    float* out = (float*)d_out;

    const int nrows = in_sizes[0] / 64;                 // 1,048,576
    const int rows_per_block = 4 * NT * 64;             // 512
    const int grid = nrows / rows_per_block;            // 2048 (exact)
    const size_t shmem = 4 * 8192;                      // 32 KiB/block

    mlp_kernel<<<grid, BLOCK, shmem, stream>>>(x, W0, b0, W1, b1, W2, b2,
                                               W3, b3, W4, b4, out, nrows);
}